// Round 6
// baseline (2012.052 us; speedup 1.0000x reference)
//
#include <hip/hip_runtime.h>
#include <hip/hip_bf16.h>
#include <hip/hip_fp16.h>

// Problem: B=64, T=1024, INPUT=256, HIDDEN=512, OUTPUT=256
//   xh = x @ W_xh + b_h
//   h_t = tanh(h_{t-1} @ W_hh + xh_t)   (serial over t)
//   out = hs @ W_hy + b_y
//
// Round 8: rocprof shows VGPR_Count=128 in EVERY prior round -> the W[48]
// (192 VGPRs) "register" weights were never resident; the backend remats the
// loads into the loop, silently streaming 384 KB/step/CU through L1/L2. That
// phantom stream is the real bottleneck (explains why LDS opts returned ~10%
// not the modeled 35%). Fix: amdgpu_waves_per_eu(2,2) pins the occupancy
// target at 2 waves/EU (256-VGPR budget) and an asm memory clobber after the
// W loads makes in-loop remat ILLEGAL. Inner loop j-granular to keep peak
// live regs ~240. gl split: col 6 via LDS, col 7 via L2 (parallel pipes).

#define BT 65536      // B*T
#define HID 512
#define NIN 256
#define NOUT 256
#define TSTEPS 1024
#define NBATCH 64

typedef _Float16 hf2_t __attribute__((ext_vector_type(2)));

__device__ __forceinline__ float fdot2(unsigned w, unsigned h, float acc) {
#if __has_builtin(__builtin_amdgcn_fdot2)
    return __builtin_amdgcn_fdot2(__builtin_bit_cast(hf2_t, w),
                                  __builtin_bit_cast(hf2_t, h), acc, false);
#else
    __half2 wv = __builtin_bit_cast(__half2, w);
    __half2 hv = __builtin_bit_cast(__half2, h);
    float2 wf = __half22float2(wv);
    float2 hf = __half22float2(hv);
    return acc + wf.x * hf.x + wf.y * hf.y;
#endif
}

__device__ __forceinline__ float dot4(uint4 w, uint4 h, float acc) {
    acc = fdot2(w.x, h.x, acc);
    acc = fdot2(w.y, h.y, acc);
    acc = fdot2(w.z, h.z, acc);
    acc = fdot2(w.w, h.w, acc);
    return acc;
}

__device__ __forceinline__ unsigned pack2h(float a, float b) {
    unsigned lo = (unsigned)__half_as_ushort(__float2half_rn(a));
    unsigned hi = (unsigned)__half_as_ushort(__float2half_rn(b));
    return lo | (hi << 16);
}

// cross-lane add via DPP (VALU pipe, no LDS).
// 0xB1 = quad_perm [1,0,3,2] (xor1), 0x4E = quad_perm [2,3,0,1] (xor2),
// 0x141 = row_half_mirror (lane -> (l&~7)|(7-(l&7))): after xor1+xor2 it
// swaps the two quad-sums within each 8-lane group = completes an 8-reduce.
template <int CTRL>
__device__ __forceinline__ float dpp_add(float x) {
    int y = __builtin_amdgcn_mov_dpp(__float_as_int(x), CTRL, 0xF, 0xF, true);
    return x + __int_as_float(y);
}
template <int CTRL>
__device__ __forceinline__ float dpp_get(float x) {
    int y = __builtin_amdgcn_mov_dpp(__float_as_int(x), CTRL, 0xF, 0xF, true);
    return __int_as_float(y);
}

// tanh(x) = 1 - 2/(e^{2x}+1); e^{2x} via v_exp_f32, division via v_rcp_f32.
__device__ __forceinline__ float fast_tanh(float x) {
    float e = __builtin_amdgcn_exp2f(x * 2.8853900817779268f);   // 2*log2(e)
    return 1.0f - 2.0f * __builtin_amdgcn_rcpf(e + 1.0f);
}

// ---------- generic load/store helpers ----------
__device__ __forceinline__ float4 load4f(const float* p) {
    return *(const float4*)p;
}
__device__ __forceinline__ float4 load4f(const __half* p) {
    ushort4 u = *(const ushort4*)p;
    float4 r;
    r.x = __half2float(__ushort_as_half(u.x));
    r.y = __half2float(__ushort_as_half(u.y));
    r.z = __half2float(__ushort_as_half(u.z));
    r.w = __half2float(__ushort_as_half(u.w));
    return r;
}
__device__ __forceinline__ void store1(float* p, float v) { *p = v; }
__device__ __forceinline__ void store1(__half* p, float v) { *p = __float2half_rn(v); }

// ---------- pack W_hh (f32 [k][col]) into per-thread f16 blobs ----------
// Scan thread t: g=t>>3, s=t&7; owns cols 8g..8g+7, k-range [64s,64s+64).
// W uint4 i = c*8+j (c=col 0..7, j=chunk 0..7): word u holds
// pack(W[64s+8j+2u][8g+c], W[64s+8j+2u+1][8g+c]).
// c<6 -> reg_blob[i][t] (48 uint4, registers); c>=6 -> gcol_blob[i-48][t]
// (16 uint4; scan serves col 6 from LDS, col 7 from L2).
__global__ __launch_bounds__(256)
void pack_w_kernel(const float* __restrict__ W,
                   unsigned* __restrict__ reg_blob,
                   unsigned* __restrict__ gcol_blob) {
    int t = blockIdx.x;      // 0..511  (scan thread id)
    int w = threadIdx.x;     // 0..255  (word index)
    int i = w >> 2, u = w & 3;
    int g = t >> 3, s = t & 7;
    int c = i >> 3, j = i & 7;
    int col = 8 * g + c;
    int k = 64 * s + 8 * j + 2 * u;
    unsigned val = pack2h(W[(size_t)k * HID + col], W[(size_t)(k + 1) * HID + col]);
    if (i < 48) reg_blob[(i * 512 + t) * 4 + u] = val;
    else        gcol_blob[((i - 48) * 512 + t) * 4 + u] = val;
}

// ---------- f32 tiled GEMM with bias: C[M,N] = A[M,K] @ B[K,N] + bias[N] ----------
// Used only for xh = x @ W_xh + b_h (precision feeds the recurrence).
template <typename AT, typename CT>
__global__ __launch_bounds__(256)
void gemm_bias_kernel(const AT* __restrict__ A, const float* __restrict__ B,
                      const float* __restrict__ bias, CT* __restrict__ C,
                      int M, int N, int K) {
    const int TM = 64, TN = 64, TK = 16;
    __shared__ float As[TK][TM];
    __shared__ float Bs[TK][TN + 4];

    int tid = threadIdx.x;
    int tx = tid & 15;
    int ty = tid >> 4;
    int row0 = blockIdx.x * TM;
    int col0 = blockIdx.y * TN;

    float c[4][4];
#pragma unroll
    for (int i = 0; i < 4; ++i)
#pragma unroll
        for (int j = 0; j < 4; ++j) c[i][j] = 0.f;

    for (int kk = 0; kk < K; kk += TK) {
        {
            int ar = tid >> 2;
            int ac = (tid & 3) * 4;
            float4 av = load4f(A + (size_t)(row0 + ar) * K + kk + ac);
            As[ac + 0][ar] = av.x;
            As[ac + 1][ar] = av.y;
            As[ac + 2][ar] = av.z;
            As[ac + 3][ar] = av.w;
        }
        {
            int br = tid >> 4;
            int bc = (tid & 15) * 4;
            float4 bv = *(const float4*)(B + (size_t)(kk + br) * N + col0 + bc);
            *(float4*)&Bs[br][bc] = bv;
        }
        __syncthreads();
#pragma unroll
        for (int k = 0; k < TK; ++k) {
            float4 a = *(const float4*)&As[k][ty * 4];
            float4 b = *(const float4*)&Bs[k][tx * 4];
            float av[4] = {a.x, a.y, a.z, a.w};
            float bv[4] = {b.x, b.y, b.z, b.w};
#pragma unroll
            for (int i = 0; i < 4; ++i)
#pragma unroll
                for (int j = 0; j < 4; ++j) c[i][j] += av[i] * bv[j];
        }
        __syncthreads();
    }

#pragma unroll
    for (int j = 0; j < 4; ++j) {
        float bb = bias[col0 + tx * 4 + j];
#pragma unroll
        for (int i = 0; i < 4; ++i) {
            int r = row0 + ty * 4 + i;
            int cc = col0 + tx * 4 + j;
            store1(&C[(size_t)r * N + cc], c[i][j] + bb);
        }
    }
}

// ---------- packed-f16 dot2 GEMM with bias (2 MACs/instr) ----------
// Used for out = hs @ W_hy + b_y: A is already f16; error does not recurse.
template <typename AT, typename CT>
__global__ __launch_bounds__(256)
void gemm_bias_f16_kernel(const AT* __restrict__ A, const float* __restrict__ B,
                          const float* __restrict__ bias, CT* __restrict__ C,
                          int M, int N, int K) {
    const int TM = 64, TN = 64, TK = 16;
    __shared__ unsigned Asp[TK / 2][TM];
    __shared__ unsigned Bsp[TK / 2][TN + 4];

    int tid = threadIdx.x;
    int tx = tid & 15;
    int ty = tid >> 4;
    int row0 = blockIdx.x * TM;
    int col0 = blockIdx.y * TN;

    float c[4][4];
#pragma unroll
    for (int i = 0; i < 4; ++i)
#pragma unroll
        for (int j = 0; j < 4; ++j) c[i][j] = 0.f;

    for (int kk = 0; kk < K; kk += TK) {
        {
            int ar = tid >> 2;
            int ac = (tid & 3) * 4;
            float4 av = load4f(A + (size_t)(row0 + ar) * K + kk + ac);
            Asp[(ac >> 1) + 0][ar] = pack2h(av.x, av.y);
            Asp[(ac >> 1) + 1][ar] = pack2h(av.z, av.w);
        }
        {
            int k2 = tid >> 5;
            int bc = (tid & 31) * 2;
            const float* b0 = B + (size_t)(kk + 2 * k2) * N + col0 + bc;
            const float* b1 = b0 + N;
            float2 r0 = *(const float2*)b0;
            float2 r1 = *(const float2*)b1;
            Bsp[k2][bc + 0] = pack2h(r0.x, r1.x);
            Bsp[k2][bc + 1] = pack2h(r0.y, r1.y);
        }
        __syncthreads();
#pragma unroll
        for (int k2 = 0; k2 < TK / 2; ++k2) {
            uint4 ap = *(const uint4*)&Asp[k2][ty * 4];
            uint4 bp = *(const uint4*)&Bsp[k2][tx * 4];
            unsigned av[4] = {ap.x, ap.y, ap.z, ap.w};
            unsigned bv[4] = {bp.x, bp.y, bp.z, bp.w};
#pragma unroll
            for (int i = 0; i < 4; ++i)
#pragma unroll
                for (int j = 0; j < 4; ++j) c[i][j] = fdot2(av[i], bv[j], c[i][j]);
        }
        __syncthreads();
    }

#pragma unroll
    for (int j = 0; j < 4; ++j) {
        float bb = bias[col0 + tx * 4 + j];
#pragma unroll
        for (int i = 0; i < 4; ++i) {
            int r = row0 + ty * 4 + i;
            int cc = col0 + tx * 4 + j;
            store1(&C[(size_t)r * N + cc], c[i][j] + bb);
        }
    }
}

// ---------- scan: one WG (one CU) per batch row, 8-way k-split ----------
// h state as 64 uint4 (256 h2), padded: slice s (8 uint4) at uint4 offset s*9
// -> the 8 per-wave broadcast addresses of read j land on bank quads
// 4(s+j)%32, all distinct. h2 index H at word ((H>>5)*9 + ((H>>2)&7))*4+(H&3).
// waves_per_eu(2,2): occupancy target pinned at 2 waves/EU -> 256-VGPR
// budget; the W[48] block (192 VGPRs) is genuinely register-resident.
template <int GLN>
__global__ __launch_bounds__(512)
__attribute__((amdgpu_waves_per_eu(2, 2)))
void rnn_scan8(const __half* __restrict__ xh,
               const uint4* __restrict__ reg_blob,    // [48][512]
               const uint4* __restrict__ gcol_blob,   // [16][512]
               __half* __restrict__ hs) {
    __shared__ __align__(16) uint4 hbuf4[2][72];      // 2304 B double-buffered h
    extern __shared__ __align__(16) uint4 gl_[];      // [GLN][512]

    const int t = threadIdx.x;
    const int b = blockIdx.x;
    const int g = t >> 3, s = t & 7;

    // 48 uint4 of weights in registers: cols 8g..8g+5, k in [64s, 64s+64)
    uint4 W[48];
#pragma unroll
    for (int i = 0; i < 48; ++i) W[i] = reg_blob[i * 512 + t];
    // Remat fence: after this point memory may have changed, so the compiler
    // cannot legally re-execute the W loads inside the loop — the 192 values
    // MUST stay in registers. (rocprof VGPR_Count is the verification bit.)
    asm volatile("" ::: "memory");

    // col 6 chunks cached in LDS (coalesced, conflict-free); col 7 stays L2
#pragma unroll
    for (int j = 0; j < GLN; ++j) gl_[j * 512 + t] = gcol_blob[j * 512 + t];

    if (t < 72) {
        hbuf4[0][t] = uint4{0u, 0u, 0u, 0u};
        hbuf4[1][t] = uint4{0u, 0u, 0u, 0u};
    }
    __syncthreads();

    const int col = 8 * g + s;
    const __half* xp = xh + (size_t)b * TSTEPS * HID + col;
    __half* hp = hs + (size_t)b * TSTEPS * HID + col;
    const uint4* gb = gcol_blob + t;

    // h2 write slot for even lanes (pair (col, col+1)):
    const int H = col >> 1;
    const int wordC = ((H >> 5) * 9 + ((H >> 2) & 7)) * 4 + (H & 3);

#define GETG(j) (((j) < GLN) ? gl_[(j) * 512 + t] : gb[(size_t)(j) * 512])

    int cur = 0;
    __half prev = __ushort_as_half((unsigned short)0);

    for (int step = 0; step < TSTEPS; ++step) {
        float xv = __half2float(xp[(size_t)step * HID]);   // issued early, used late
        if (step) hp[(size_t)(step - 1) * HID] = prev;     // delayed store

        const uint4* hv = &hbuf4[cur][s * 9];
        float acc[8];
#pragma unroll
        for (int c = 0; c < 8; ++c) acc[c] = 0.f;

        // j-granular: 1 h uint4 + 1 LDS gl + 1 L2 gl + 8 dot4 per j keeps
        // peak live VGPRs ~240 (< the 256 budget; round-6 lesson)
#pragma unroll
        for (int j = 0; j < 8; ++j) {
            uint4 hj = hv[j];
            uint4 gA = GETG(j);          // col 6: LDS
            uint4 gB = GETG(8 + j);      // col 7: L2 (loop-invariant addrs)
            acc[0] = dot4(W[0 * 8 + j], hj, acc[0]);
            acc[1] = dot4(W[1 * 8 + j], hj, acc[1]);
            acc[2] = dot4(W[2 * 8 + j], hj, acc[2]);
            acc[3] = dot4(W[3 * 8 + j], hj, acc[3]);
            acc[4] = dot4(W[4 * 8 + j], hj, acc[4]);
            acc[5] = dot4(W[5 * 8 + j], hj, acc[5]);
            acc[6] = dot4(gA, hj, acc[6]);
            acc[7] = dot4(gB, hj, acc[7]);
        }
#undef GETG

        // 8-lane reduce entirely on the VALU: xor1, xor2 (quad_perm), then
        // row_half_mirror swaps the two quad-sums of each 8-lane group.
#pragma unroll
        for (int c = 0; c < 8; ++c) {
            acc[c] = dpp_add<0xB1>(acc[c]);
            acc[c] = dpp_add<0x4E>(acc[c]);
            acc[c] = dpp_add<0x141>(acc[c]);
        }

        // lane s finalizes col 8g+s (compares are loop-invariant -> hoisted)
        float tot = acc[0];
        tot = (s == 1) ? acc[1] : tot;
        tot = (s == 2) ? acc[2] : tot;
        tot = (s == 3) ? acc[3] : tot;
        tot = (s == 4) ? acc[4] : tot;
        tot = (s == 5) ? acc[5] : tot;
        tot = (s == 6) ? acc[6] : tot;
        tot = (s == 7) ? acc[7] : tot;

        float hn = fast_tanh(tot + xv);
        prev = __float2half_rn(hn);

        // pack (col, col+1) via DPP xor1; even lane writes the h2 word
        float hi = dpp_get<0xB1>(hn);
        unsigned* hwp = (unsigned*)&hbuf4[cur ^ 1][0];
        if (!(s & 1)) hwp[wordC] = pack2h(hn, hi);
        __syncthreads();
        cur ^= 1;
    }
    hp[(size_t)(TSTEPS - 1) * HID] = prev;
}

extern "C" void kernel_launch(void* const* d_in, const int* in_sizes, int n_in,
                              void* d_out, int out_size, void* d_ws, size_t ws_size,
                              hipStream_t stream) {
    const float* x    = (const float*)d_in[0];   // [64,1024,256]
    const float* W_xh = (const float*)d_in[1];   // [256,512]
    const float* W_hh = (const float*)d_in[2];   // [512,512]
    const float* b_h  = (const float*)d_in[3];   // [512]
    const float* W_hy = (const float*)d_in[4];   // [512,256]
    const float* b_y  = (const float*)d_in[5];   // [256]
    float* out = (float*)d_out;                  // [64,1024,256]

    char* ws = (char*)d_ws;
    const size_t off_gcol = 48 * 512 * 16;                  // 384 KiB
    const size_t off_xh   = (size_t)1 << 20;                // 1 MiB
    const size_t off_hs   = off_xh + (size_t)BT * HID * 2;  // +64 MiB

    unsigned* reg_blob  = (unsigned*)ws;
    unsigned* gcol_blob = (unsigned*)(ws + off_gcol);
    __half*   xh        = (__half*)(ws + off_xh);
    __half*   hs        = (__half*)(ws + off_hs);

    // 1) pack W_hh -> per-thread f16 blobs (8-way-split geometry)
    pack_w_kernel<<<dim3(512), dim3(256), 0, stream>>>(W_hh, reg_blob, gcol_blob);

    // 2) xh = x @ W_xh + b_h   (f32 math -> f16 C; feeds the recurrence)
    gemm_bias_kernel<float, __half>
        <<<dim3(BT / 64, HID / 64), dim3(256), 0, stream>>>(x, W_xh, b_h, xh, BT, HID, NIN);

    // 3) scan: 64 WGs, one per batch row; col-6 gl chunks in 64 KiB dynamic
    //    LDS, col-7 from L2 (parallel pipes). Fallback GLN=7 if opt-in fails.
    const int GLDS_BYTES = 8 * 512 * 16;        // 65536
    hipError_t e = hipFuncSetAttribute(
        reinterpret_cast<const void*>(&rnn_scan8<8>),
        hipFuncAttributeMaxDynamicSharedMemorySize, GLDS_BYTES);
    if (e == hipSuccess) {
        rnn_scan8<8><<<dim3(NBATCH), dim3(512), GLDS_BYTES, stream>>>(
            xh, (const uint4*)reg_blob, (const uint4*)gcol_blob, hs);
    } else {
        (void)hipGetLastError();                // clear non-sticky error state
        rnn_scan8<7><<<dim3(NBATCH), dim3(512), 7 * 512 * 16, stream>>>(
            xh, (const uint4*)reg_blob, (const uint4*)gcol_blob, hs);
    }

    // 4) out = hs @ W_hy + b_y   (packed f16 dot2; error does not recurse)
    gemm_bias_f16_kernel<__half, float>
        <<<dim3(BT / 64, NOUT / 64), dim3(256), 0, stream>>>(hs, W_hy, b_y, out, BT, NOUT, HID);
}

// Round 7
// 1520.009 us; speedup vs baseline: 1.3237x; 1.3237x over previous
//
#include <hip/hip_runtime.h>
#include <hip/hip_bf16.h>
#include <hip/hip_fp16.h>

// Problem: B=64, T=1024, INPUT=256, HIDDEN=512, OUTPUT=256
//   xh = x @ W_xh + b_h
//   h_t = tanh(h_{t-1} @ W_hh + xh_t)   (serial over t)
//   out = hs @ W_hy + b_y
//
// Round 9: 4-CU column split. Evidence from rounds 7/8: the allocator caps
// this kernel at ~128 VGPRs, so the single-CU structure MUST stream >=200KB
// of W_hh per step from L2 (~3300 cy) - round 7 is at that structural limit.
// Round 4's "cross-WG exchange unaffordable" was confounded (VGPR=84 there:
// W streamed too). New design: 256 WGs (1/CU), each owns 128 cols x full k
// -> per-thread W = 16 uint4 = 64 VGPRs, genuinely register-resident, zero
// weight streaming. Per-step h exchange is lock-free: one u64 atomic word
// packs (tag, 2xf16) so a successful poll IS the data (no flag round-trip,
// no fences). Parity double-buffer + monotonic tags + per-launch zeroing
// (graph-replay-safe). Group {row, row+64, +128, +192} shares bid%8 -> same
// XCD under the round-robin heuristic (perf-only; agent atomics correct
// regardless). Co-residency: 1 WG/CU max resources -> all 256 resident.

#define BT 65536      // B*T
#define HID 512
#define NIN 256
#define NOUT 256
#define TSTEPS 1024
#define NBATCH 64

typedef _Float16 hf2_t __attribute__((ext_vector_type(2)));

__device__ __forceinline__ float fdot2(unsigned w, unsigned h, float acc) {
#if __has_builtin(__builtin_amdgcn_fdot2)
    return __builtin_amdgcn_fdot2(__builtin_bit_cast(hf2_t, w),
                                  __builtin_bit_cast(hf2_t, h), acc, false);
#else
    __half2 wv = __builtin_bit_cast(__half2, w);
    __half2 hv = __builtin_bit_cast(__half2, h);
    float2 wf = __half22float2(wv);
    float2 hf = __half22float2(hv);
    return acc + wf.x * hf.x + wf.y * hf.y;
#endif
}

__device__ __forceinline__ float dot4(uint4 w, uint4 h, float acc) {
    acc = fdot2(w.x, h.x, acc);
    acc = fdot2(w.y, h.y, acc);
    acc = fdot2(w.z, h.z, acc);
    acc = fdot2(w.w, h.w, acc);
    return acc;
}

__device__ __forceinline__ unsigned pack2h(float a, float b) {
    unsigned lo = (unsigned)__half_as_ushort(__float2half_rn(a));
    unsigned hi = (unsigned)__half_as_ushort(__float2half_rn(b));
    return lo | (hi << 16);
}

// cross-lane add via DPP (VALU pipe, no LDS).
// 0xB1 = quad_perm xor1, 0x4E = quad_perm xor2, 0x141 = row_half_mirror
// (after xor1+xor2, swaps the two quad-sums of each 8-lane group -> 8-reduce).
template <int CTRL>
__device__ __forceinline__ float dpp_add(float x) {
    int y = __builtin_amdgcn_mov_dpp(__float_as_int(x), CTRL, 0xF, 0xF, true);
    return x + __int_as_float(y);
}
template <int CTRL>
__device__ __forceinline__ float dpp_get(float x) {
    int y = __builtin_amdgcn_mov_dpp(__float_as_int(x), CTRL, 0xF, 0xF, true);
    return __int_as_float(y);
}

// tanh(x) = 1 - 2/(e^{2x}+1); e^{2x} via v_exp_f32, division via v_rcp_f32.
__device__ __forceinline__ float fast_tanh(float x) {
    float e = __builtin_amdgcn_exp2f(x * 2.8853900817779268f);   // 2*log2(e)
    return 1.0f - 2.0f * __builtin_amdgcn_rcpf(e + 1.0f);
}

// ---------- generic load/store helpers ----------
__device__ __forceinline__ float4 load4f(const float* p) {
    return *(const float4*)p;
}
__device__ __forceinline__ float4 load4f(const __half* p) {
    ushort4 u = *(const ushort4*)p;
    float4 r;
    r.x = __half2float(__ushort_as_half(u.x));
    r.y = __half2float(__ushort_as_half(u.y));
    r.z = __half2float(__ushort_as_half(u.z));
    r.w = __half2float(__ushort_as_half(u.w));
    return r;
}
__device__ __forceinline__ void store1(float* p, float v) { *p = v; }
__device__ __forceinline__ void store1(__half* p, float v) { *p = __float2half_rn(v); }

// ---------- pack W_hh (f32 [k][col]) into per-thread f16 blobs ----------
// Scan WG quarter q, thread t (g=t>>3, s=t&7): cols {128q+2g, 128q+2g+1},
// k in [64s, 64s+64). W uint4 i = c*8+j (c=0..1, j=0..7), word u:
// pack(W[64s+8j+2u][128q+2g+c], W[64s+8j+2u+1][...]).
// Layout wblob[(q*16+i)*512 + t] (uint4), coalesced on t.
// Also zeroes the 32768-u64 exchange buffer (per-launch tag reset).
__global__ __launch_bounds__(256)
void pack_w4_kernel(const float* __restrict__ W,
                    unsigned* __restrict__ wblob_w,
                    unsigned long long* __restrict__ exch) {
    int w = blockIdx.x * 256 + threadIdx.x;   // 0..131071
    int q = w >> 15;
    int r = w & 32767;
    int i = r >> 11;
    int r2 = r & 2047;
    int t = r2 >> 2, u = r2 & 3;
    int g = t >> 3, s = t & 7;
    int c = i >> 3, j = i & 7;
    int col = 128 * q + 2 * g + c;
    int k = 64 * s + 8 * j + 2 * u;
    unsigned val = pack2h(W[(size_t)k * HID + col], W[(size_t)(k + 1) * HID + col]);
    wblob_w[(size_t)((q * 16 + i) * 512 + t) * 4 + u] = val;
    if (w < 32768) exch[w] = 0ull;            // graph-replay-safe tag reset
}

// ---------- f32 tiled GEMM with bias: C[M,N] = A[M,K] @ B[K,N] + bias[N] ----------
// Used only for xh = x @ W_xh + b_h (precision feeds the recurrence).
template <typename AT, typename CT>
__global__ __launch_bounds__(256)
void gemm_bias_kernel(const AT* __restrict__ A, const float* __restrict__ B,
                      const float* __restrict__ bias, CT* __restrict__ C,
                      int M, int N, int K) {
    const int TM = 64, TN = 64, TK = 16;
    __shared__ float As[TK][TM];
    __shared__ float Bs[TK][TN + 4];

    int tid = threadIdx.x;
    int tx = tid & 15;
    int ty = tid >> 4;
    int row0 = blockIdx.x * TM;
    int col0 = blockIdx.y * TN;

    float c[4][4];
#pragma unroll
    for (int i = 0; i < 4; ++i)
#pragma unroll
        for (int j = 0; j < 4; ++j) c[i][j] = 0.f;

    for (int kk = 0; kk < K; kk += TK) {
        {
            int ar = tid >> 2;
            int ac = (tid & 3) * 4;
            float4 av = load4f(A + (size_t)(row0 + ar) * K + kk + ac);
            As[ac + 0][ar] = av.x;
            As[ac + 1][ar] = av.y;
            As[ac + 2][ar] = av.z;
            As[ac + 3][ar] = av.w;
        }
        {
            int br = tid >> 4;
            int bc = (tid & 15) * 4;
            float4 bv = *(const float4*)(B + (size_t)(kk + br) * N + col0 + bc);
            *(float4*)&Bs[br][bc] = bv;
        }
        __syncthreads();
#pragma unroll
        for (int k = 0; k < TK; ++k) {
            float4 a = *(const float4*)&As[k][ty * 4];
            float4 b = *(const float4*)&Bs[k][tx * 4];
            float av[4] = {a.x, a.y, a.z, a.w};
            float bv[4] = {b.x, b.y, b.z, b.w};
#pragma unroll
            for (int i = 0; i < 4; ++i)
#pragma unroll
                for (int j = 0; j < 4; ++j) c[i][j] += av[i] * bv[j];
        }
        __syncthreads();
    }

#pragma unroll
    for (int j = 0; j < 4; ++j) {
        float bb = bias[col0 + tx * 4 + j];
#pragma unroll
        for (int i = 0; i < 4; ++i) {
            int r = row0 + ty * 4 + i;
            int cc = col0 + tx * 4 + j;
            store1(&C[(size_t)r * N + cc], c[i][j] + bb);
        }
    }
}

// ---------- packed-f16 dot2 GEMM with bias (2 MACs/instr) ----------
// Used for out = hs @ W_hy + b_y: A is already f16; error does not recurse.
template <typename AT, typename CT>
__global__ __launch_bounds__(256)
void gemm_bias_f16_kernel(const AT* __restrict__ A, const float* __restrict__ B,
                          const float* __restrict__ bias, CT* __restrict__ C,
                          int M, int N, int K) {
    const int TM = 64, TN = 64, TK = 16;
    __shared__ unsigned Asp[TK / 2][TM];
    __shared__ unsigned Bsp[TK / 2][TN + 4];

    int tid = threadIdx.x;
    int tx = tid & 15;
    int ty = tid >> 4;
    int row0 = blockIdx.x * TM;
    int col0 = blockIdx.y * TN;

    float c[4][4];
#pragma unroll
    for (int i = 0; i < 4; ++i)
#pragma unroll
        for (int j = 0; j < 4; ++j) c[i][j] = 0.f;

    for (int kk = 0; kk < K; kk += TK) {
        {
            int ar = tid >> 2;
            int ac = (tid & 3) * 4;
            float4 av = load4f(A + (size_t)(row0 + ar) * K + kk + ac);
            Asp[(ac >> 1) + 0][ar] = pack2h(av.x, av.y);
            Asp[(ac >> 1) + 1][ar] = pack2h(av.z, av.w);
        }
        {
            int k2 = tid >> 5;
            int bc = (tid & 31) * 2;
            const float* b0 = B + (size_t)(kk + 2 * k2) * N + col0 + bc;
            const float* b1 = b0 + N;
            float2 r0 = *(const float2*)b0;
            float2 r1 = *(const float2*)b1;
            Bsp[k2][bc + 0] = pack2h(r0.x, r1.x);
            Bsp[k2][bc + 1] = pack2h(r0.y, r1.y);
        }
        __syncthreads();
#pragma unroll
        for (int k2 = 0; k2 < TK / 2; ++k2) {
            uint4 ap = *(const uint4*)&Asp[k2][ty * 4];
            uint4 bp = *(const uint4*)&Bsp[k2][tx * 4];
            unsigned av[4] = {ap.x, ap.y, ap.z, ap.w};
            unsigned bv[4] = {bp.x, bp.y, bp.z, bp.w};
#pragma unroll
            for (int i = 0; i < 4; ++i)
#pragma unroll
                for (int j = 0; j < 4; ++j) c[i][j] = fdot2(av[i], bv[j], c[i][j]);
        }
        __syncthreads();
    }

#pragma unroll
    for (int j = 0; j < 4; ++j) {
        float bb = bias[col0 + tx * 4 + j];
#pragma unroll
        for (int i = 0; i < 4; ++i) {
            int r = row0 + ty * 4 + i;
            int cc = col0 + tx * 4 + j;
            store1(&C[(size_t)r * N + cc], c[i][j] + bb);
        }
    }
}

// ---------- scan: 4 WGs per batch row (column quarters), all-reg W ----------
// h2-index H (0..255) lives at LDS word (H>>5)*36 + (H&31)  (uint4-slot
// stride 9 per 8: slice s's 8 uint4 start at slot s*9 -> the 8 per-wave
// broadcast reads hit disjoint bank quads).
// exch word: [row][parity][quarter][g] u64 = (tag<<32) | packed 2xf16.
// tag = step+1, parity = (step+1)&1; consumer at step t polls tag >= t.
__global__ __launch_bounds__(512, 2)
void rnn_scan4(const __half* __restrict__ xh,
               const uint4* __restrict__ wblob,            // [4][16][512]
               __half* __restrict__ hs,
               unsigned long long* __restrict__ exch) {    // [64][2][4][64]
    __shared__ __align__(16) uint4 hbuf4[2][72];           // 2304 B, h double-buffer

    const int bid = blockIdx.x;          // 0..255
    const int row = bid & 63;            // batch row; group shares bid%8 (XCD)
    const int q   = bid >> 6;            // column quarter: cols [128q,128q+128)
    const int t = threadIdx.x;
    const int g = t >> 3, s = t & 7;     // col pair group / k-slice [64s,64s+64)

    // whole weight slice in registers: 16 uint4 = 64 VGPRs (fits the ~128 cap)
    uint4 W[16];
#pragma unroll
    for (int i = 0; i < 16; ++i) W[i] = wblob[(q * 16 + i) * 512 + t];

    if (t < 72) {
        hbuf4[0][t] = uint4{0u, 0u, 0u, 0u};
        hbuf4[1][t] = uint4{0u, 0u, 0u, 0u};
    }
    __syncthreads();

    const int col0 = 128 * q + 2 * g;    // lane s<2 finalizes col0+s
    const __half* xp = xh + (size_t)row * TSTEPS * HID + col0 + s;
    // hs output as u32 (h2 pair): base word = row*T*256 + (64q+g), +256/step
    unsigned* hp32 = (unsigned*)hs + (size_t)row * TSTEPS * 256 + (64 * q + g);
    // own-quarter LDS write slot: H = 64q+g
    const int wordC = ((64 * q + g) >> 5) * 36 + ((64 * q + g) & 31);
    // publish pointers (per parity)
    unsigned long long* pub[2];
    pub[0] = exch + (((size_t)row * 2 + 0) * 4 + q) * 64 + g;
    pub[1] = exch + (((size_t)row * 2 + 1) * 4 + q) * 64 + g;
    // loader role: threads 0..191 fetch the 3 partner quarters (64 u64 each)
    const int m = t & 63;
    const int qa = t >> 6;                           // 0..2 for loaders
    const int Q = qa + (qa >= q ? 1 : 0);            // absolute partner quarter
    const unsigned long long* src[2];
    src[0] = exch + (((size_t)row * 2 + 0) * 4 + Q) * 64 + m;
    src[1] = exch + (((size_t)row * 2 + 1) * 4 + Q) * 64 + m;
    const int ldsw = ((64 * Q + m) >> 5) * 36 + ((64 * Q + m) & 31);

    for (int step = 0; step < TSTEPS; ++step) {
        const int par = step & 1;

        float xv = 0.f;
        if (s < 2) xv = __half2float(xp[(size_t)step * HID]);   // early issue

        if (step && t < 192) {
            // poll: a successful read carries the data (tag+payload in one u64)
            unsigned long long v = __hip_atomic_load(
                src[par], __ATOMIC_RELAXED, __HIP_MEMORY_SCOPE_AGENT);
            while ((unsigned)(v >> 32) < (unsigned)step) {
                v = __hip_atomic_load(src[par], __ATOMIC_RELAXED,
                                      __HIP_MEMORY_SCOPE_AGENT);
            }
            ((unsigned*)&hbuf4[par][0])[ldsw] = (unsigned)v;
        }
        __syncthreads();

        // dots: 8 broadcast h uint4 (slice s) x 16 reg W -> 2 column sums
        const uint4* hv = &hbuf4[par][s * 9];
        float a0 = 0.f, a1 = 0.f;
#pragma unroll
        for (int j = 0; j < 8; ++j) {
            uint4 hj = hv[j];
            a0 = dot4(W[j], hj, a0);
            a1 = dot4(W[8 + j], hj, a1);
        }

        // 8-lane reduce on the VALU (xor1, xor2, half-mirror)
        a0 = dpp_add<0xB1>(a0); a0 = dpp_add<0x4E>(a0); a0 = dpp_add<0x141>(a0);
        a1 = dpp_add<0xB1>(a1); a1 = dpp_add<0x4E>(a1); a1 = dpp_add<0x141>(a1);

        if (s < 2) {
            float tot = (s == 0) ? a0 : a1;
            float hn = fast_tanh(tot + xv);
            float hi = dpp_get<0xB1>(hn);        // lane0 pulls lane1's value
            if (s == 0) {
                unsigned pv = pack2h(hn, hi);
                ((unsigned*)&hbuf4[par ^ 1][0])[wordC] = pv;   // own next-state
                hp32[(size_t)step * 256] = pv;                 // hs output
                unsigned long long pubv =
                    ((unsigned long long)(unsigned)(step + 1) << 32) | pv;
                __hip_atomic_store(pub[(step + 1) & 1], pubv,
                                   __ATOMIC_RELAXED, __HIP_MEMORY_SCOPE_AGENT);
            }
        }
        // no end barrier: next step's __syncthreads orders hbuf[par^1] writes
    }
}

extern "C" void kernel_launch(void* const* d_in, const int* in_sizes, int n_in,
                              void* d_out, int out_size, void* d_ws, size_t ws_size,
                              hipStream_t stream) {
    const float* x    = (const float*)d_in[0];   // [64,1024,256]
    const float* W_xh = (const float*)d_in[1];   // [256,512]
    const float* W_hh = (const float*)d_in[2];   // [512,512]
    const float* b_h  = (const float*)d_in[3];   // [512]
    const float* W_hy = (const float*)d_in[4];   // [512,256]
    const float* b_y  = (const float*)d_in[5];   // [256]
    float* out = (float*)d_out;                  // [64,1024,256]

    char* ws = (char*)d_ws;
    unsigned* wblob = (unsigned*)ws;                              // 512 KiB
    unsigned long long* exch = (unsigned long long*)(ws + (512 << 10)); // 256 KiB
    __half* xh = (__half*)(ws + (1 << 20));                       // 64 MiB
    __half* hs = (__half*)(ws + (1 << 20) + (size_t)BT * HID * 2);// 64 MiB

    // 1) pack W_hh -> per-thread f16 blobs (4-CU-split geometry) + zero exch
    pack_w4_kernel<<<dim3(512), dim3(256), 0, stream>>>(W_hh, wblob, exch);

    // 2) xh = x @ W_xh + b_h   (f32 math -> f16 C; feeds the recurrence)
    gemm_bias_kernel<float, __half>
        <<<dim3(BT / 64, HID / 64), dim3(256), 0, stream>>>(x, W_xh, b_h, xh, BT, HID, NIN);

    // 3) scan: 256 WGs = 64 rows x 4 column-quarters, lock-free u64 exchange
    rnn_scan4<<<dim3(4 * NBATCH), dim3(512), 0, stream>>>(
        xh, (const uint4*)wblob, hs, exch);

    // 4) out = hs @ W_hy + b_y   (packed f16 dot2; error does not recurse)
    gemm_bias_f16_kernel<__half, float>
        <<<dim3(BT / 64, NOUT / 64), dim3(256), 0, stream>>>(hs, W_hy, b_y, out, BT, NOUT, HID);
}